// Round 3
// baseline (222.803 us; speedup 1.0000x reference)
//
#include <hip/hip_runtime.h>

#define ETA_MIN 0.6931471805599453f
#define ETA_MAX 10.0f

// Native vector type — lowers to global_{load,store}_dwordx4.
typedef float vfloat4 __attribute__((ext_vector_type(4)));

// Streaming elementwise: w_i = (loss_i > eta) ? 0 : 1 - loss_i/eta,
// eta = clamp(eta_value[0], log(2), 10).
//
// Structure notes from this session's A/Bs:
//  - one-shot 1 float4/thread (R0) == 2 float4/thread (R2) within noise;
//    grid-stride unroll-4 (R1) REGRESSED (loop-carried vmcnt serialization).
//    TLP at 32 waves/CU already pipelines the stream -> keep simplest form.
//  - This round's A/B: plain (L2-cached) loads/stores instead of
//    non-temporal. The 6.6 TB/s poison fills and the 6.29 TB/s m13 copy
//    µbench both go through L2; nt bypass forfeits L2 write aggregation
//    in front of the HBM controllers. Zero-reuse pollution is a non-issue
//    (268 MB stream vs 256 MB L3).
__global__ void __launch_bounds__(256) weights_kernel(
    const float* __restrict__ loss,
    const float* __restrict__ eta_value,
    float* __restrict__ out,
    int n4,          // number of float4 elements
    int tail_start,  // n4*4
    int n)           // total elements
{
    // Uniform load — scalar path, negligible.
    float eta = eta_value[0];
    eta = fminf(fmaxf(eta, ETA_MIN), ETA_MAX);
    const float inv = 1.0f / eta;

    const int i = blockIdx.x * blockDim.x + threadIdx.x;

    const vfloat4* __restrict__ in4  = reinterpret_cast<const vfloat4*>(loss);
    vfloat4*       __restrict__ out4 = reinterpret_cast<vfloat4*>(out);

    if (i < n4) {
        const vfloat4 l = in4[i];
        vfloat4 w;
        w.x = (l.x > eta) ? 0.0f : fmaf(-l.x, inv, 1.0f);
        w.y = (l.y > eta) ? 0.0f : fmaf(-l.y, inv, 1.0f);
        w.z = (l.z > eta) ? 0.0f : fmaf(-l.z, inv, 1.0f);
        w.w = (l.w > eta) ? 0.0f : fmaf(-l.w, inv, 1.0f);
        out4[i] = w;
    }

    // Scalar tail (n not divisible by 4). Dead for N=2^25.
    const int t = tail_start + i;
    if (i < n - tail_start) {
        const float l = loss[t];
        out[t] = (l > eta) ? 0.0f : fmaf(-l, inv, 1.0f);
    }
}

extern "C" void kernel_launch(void* const* d_in, const int* in_sizes, int n_in,
                              void* d_out, int out_size, void* d_ws, size_t ws_size,
                              hipStream_t stream) {
    const float* loss = (const float*)d_in[0];
    const float* eta  = (const float*)d_in[1];
    float* out        = (float*)d_out;
    const int n  = in_sizes[0];
    const int n4 = n / 4;
    const int tail_start = n4 * 4;

    const int block = 256;
    int work = n4 > (n - tail_start) ? n4 : (n - tail_start);
    if (work < 1) work = 1;
    const int grid = (work + block - 1) / block;

    weights_kernel<<<grid, block, 0, stream>>>(loss, eta, out, n4, tail_start, n);
}